// Round 13
// baseline (189.508 us; speedup 1.0000x reference)
//
#include <hip/hip_runtime.h>
#include <math.h>

#define TT 2048
#define DD 1024
#define NH 16
#define DHD 64
#define DFF 4096

typedef __attribute__((ext_vector_type(8))) short short8;
typedef __attribute__((ext_vector_type(4))) float f32x4;

#define MFMA16(a, b, c) __builtin_amdgcn_mfma_f32_16x16x32_bf16(a, b, c, 0, 0, 0)
#define GLDS16(gp, lp) __builtin_amdgcn_global_load_lds( \
    (const __attribute__((address_space(1))) void*)(gp), \
    (__attribute__((address_space(3))) void*)(lp), 16, 0, 0)

static __device__ __forceinline__ unsigned short f2b(float f) {
  unsigned u = __builtin_bit_cast(unsigned, f);
  u = u + 0x7fffu + ((u >> 16) & 1u);
  return (unsigned short)(u >> 16);
}
static __device__ __forceinline__ float b2f(unsigned short b) {
  return __builtin_bit_cast(float, (unsigned)b << 16);
}

// ---------------- fp32 -> bf16 convert; w_kqv rows PERMUTED head-contiguous -
__global__ __launch_bounds__(256) void f2b4_kernel(const float* __restrict__ s0,
    const float* __restrict__ s1, const float* __restrict__ s2,
    const float* __restrict__ s3, unsigned short* __restrict__ out) {
  int i = blockIdx.x * 256 + threadIdx.x;
  float4 v;
  if (i < 786432) {
    int row = i >> 8, kk = i & 255;
    int sec = row >> 10, wi = row & 1023;
    int src = (sec << 10) + ((wi & 63) << 4) + (wi >> 6);
    v = ((const float4*)s0)[(src << 8) + kk];
  } else if (i < 1048576) {
    v = ((const float4*)s1)[i - 786432];
  } else if (i < 2097152) {
    v = ((const float4*)s2)[i - 1048576];
  } else {
    v = ((const float4*)s3)[i - 2097152];
  }
  ushort4 o;
  o.x = f2b(v.x); o.y = f2b(v.y); o.z = f2b(v.z); o.w = f2b(v.w);
  ((ushort4*)out)[i] = o;
}

// ---------------- LayerNorm (fp32 in, bf16 out) ----------------
__global__ __launch_bounds__(256) void ln_kernel(const float* __restrict__ x,
    const float* __restrict__ w, const float* __restrict__ b,
    unsigned short* __restrict__ out) {
  int row = blockIdx.x;
  const float4* xr = (const float4*)(x + (size_t)row * DD);
  float4 v = xr[threadIdx.x];
  float s  = v.x + v.y + v.z + v.w;
  float ss = v.x * v.x + v.y * v.y + v.z * v.z + v.w * v.w;
  for (int o = 32; o > 0; o >>= 1) {
    s  += __shfl_down(s, o);
    ss += __shfl_down(ss, o);
  }
  __shared__ float red[10];
  int lane = threadIdx.x & 63, wv = threadIdx.x >> 6;
  if (lane == 0) { red[wv] = s; red[4 + wv] = ss; }
  __syncthreads();
  if (threadIdx.x == 0) {
    float S  = red[0] + red[1] + red[2] + red[3];
    float SS = red[4] + red[5] + red[6] + red[7];
    float mu  = S * (1.0f / DD);
    float var = SS * (1.0f / DD) - mu * mu;
    red[8] = mu;
    red[9] = rsqrtf(var + 1e-5f);
  }
  __syncthreads();
  float mu = red[8], inv = red[9];
  float4 wv4 = ((const float4*)w)[threadIdx.x];
  float4 bv4 = ((const float4*)b)[threadIdx.x];
  ushort4 o4;
  o4.x = f2b((v.x - mu) * inv * wv4.x + bv4.x);
  o4.y = f2b((v.y - mu) * inv * wv4.y + bv4.y);
  o4.z = f2b((v.z - mu) * inv * wv4.z + bv4.z);
  o4.w = f2b((v.w - mu) * inv * wv4.w + bv4.w);
  ((ushort4*)(out + (size_t)row * DD))[threadIdx.x] = o4;
}

// ---------------- bf16 MFMA GEMM v6 (unchanged, proven): 128x128, BK=32 -----
__global__ __launch_bounds__(256, 4) void gemm6(
    const unsigned short* __restrict__ A,   // [M,K] bf16
    const unsigned short* __restrict__ Bw,  // [N,K] bf16
    unsigned short* __restrict__ Cp,        // partials, bz < SPLITA
    unsigned short* __restrict__ Cp2,       // partials, bz >= SPLITA
    int M, int N, int K, int KS, int CX, int CY, int SPLITA) {
  __shared__ char lds[32768];
  const int tid = threadIdx.x;
  const int w = tid >> 6, l = tid & 63;
  const int l15 = l & 15, lhi = l >> 4;

  const int GX = N >> 7, GYM = M >> 7;
  const int xcd = blockIdx.x & 7, s = blockIdx.x >> 3;
  const int ncx = GX / CX;
  const int bx = (xcd % ncx) * CX + (s % CX);
  const int yz = (xcd / ncx) * CY + (s / CX);
  const int by = yz % GYM, bz = yz / GYM;

  const int row0 = by << 7, col0 = bx << 7;
  const int kbeg = bz * KS;
  const int wm = (w >> 1) * 64, wn = (w & 1) * 64;

  f32x4 acc[4][4] = {};

  const int srow = w * 32 + (l >> 2);
  const int scol = (l & 3) * 16;
  const char* aS = (const char*)A + ((size_t)(row0 + srow) * K + kbeg) * 2 + scol;
  const char* bS = (const char*)Bw + ((size_t)(col0 + srow) * K + kbeg) * 2 + scol;
  const size_t r16 = (size_t)K * 32;
  const int aO = w * 2048, bO = 8192 + w * 2048;
  const int NT = KS >> 5;

  auto STAGE = [&](int t) {
    char* base = lds + (t & 1) * 16384;
    const char* a = aS + (size_t)t * 64;
    const char* b = bS + (size_t)t * 64;
    GLDS16(a,       base + aO);
    GLDS16(a + r16, base + aO + 1024);
    GLDS16(b,       base + bO);
    GLDS16(b + r16, base + bO + 1024);
  };
  auto COMPUTE = [&](int t) {
    const char* Ab = lds + (t & 1) * 16384;
    const char* Bb = Ab + 8192;
    short8 af[4], bf[4];
#pragma unroll
    for (int mi = 0; mi < 4; ++mi)
      af[mi] = *(const short8*)(Ab + (wm + mi * 16 + l15) * 64 + lhi * 16);
#pragma unroll
    for (int ni = 0; ni < 4; ++ni)
      bf[ni] = *(const short8*)(Bb + (wn + ni * 16 + l15) * 64 + lhi * 16);
    __builtin_amdgcn_s_setprio(1);
#pragma unroll
    for (int mi = 0; mi < 4; ++mi)
#pragma unroll
      for (int ni = 0; ni < 4; ++ni)
        acc[mi][ni] = MFMA16(af[mi], bf[ni], acc[mi][ni]);
    __builtin_amdgcn_s_setprio(0);
  };

  STAGE(0);
  for (int t = 0; t < NT; ++t) {
    if (t + 1 < NT) STAGE(t + 1);
    __builtin_amdgcn_sched_barrier(0);
    if (t + 1 < NT) asm volatile("s_waitcnt vmcnt(4)" ::: "memory");
    else            asm volatile("s_waitcnt vmcnt(0)" ::: "memory");
    __builtin_amdgcn_s_barrier();
    __builtin_amdgcn_sched_barrier(0);
    COMPUTE(t);
    __builtin_amdgcn_sched_barrier(0);
    __builtin_amdgcn_s_barrier();
  }

  unsigned short* base;
  size_t off;
  if (bz < SPLITA) { base = Cp;  off = (size_t)bz * M * N; }
  else             { base = Cp2; off = (size_t)(bz - SPLITA) * M * N; }
#pragma unroll
  for (int mi = 0; mi < 4; ++mi)
#pragma unroll
    for (int r = 0; r < 4; ++r) {
      size_t row = (size_t)(row0 + wm + mi * 16 + lhi * 4 + r);
#pragma unroll
      for (int ni = 0; ni < 4; ++ni)
        base[off + row * N + col0 + wn + ni * 16 + l15] = f2b(acc[mi][ni][r]);
    }
}

// ------- reduce: 2 bf16 partials + bias; MODE 0=plain,1=gelu,2=kqv(Q x8) ----
template<int MODE>
__global__ __launch_bounds__(256) void reduce2b(const unsigned short* __restrict__ p0,
    const unsigned short* __restrict__ p1, const float* __restrict__ bias,
    unsigned short* __restrict__ out, int n4) {
  int i = blockIdx.x * 256 + threadIdx.x;
  ushort4 a = ((const ushort4*)p0)[i];
  ushort4 b = ((const ushort4*)p1)[i];
  float4 bb = ((const float4*)bias)[i % n4];
  float v0 = b2f(a.x) + b2f(b.x) + bb.x;
  float v1 = b2f(a.y) + b2f(b.y) + bb.y;
  float v2 = b2f(a.z) + b2f(b.z) + bb.z;
  float v3 = b2f(a.w) + b2f(b.w) + bb.w;
  if (MODE == 1) {
    const float c = 0.7978845608028654f;
    v0 = 0.5f * v0 * (1.0f + tanhf(c * (v0 + 0.044715f * v0 * v0 * v0)));
    v1 = 0.5f * v1 * (1.0f + tanhf(c * (v1 + 0.044715f * v1 * v1 * v1)));
    v2 = 0.5f * v2 * (1.0f + tanhf(c * (v2 + 0.044715f * v2 * v2 * v2)));
    v3 = 0.5f * v3 * (1.0f + tanhf(c * (v3 + 0.044715f * v3 * v3 * v3)));
  }
  if (MODE == 2) {
    int c4 = i % 768;                       // float4-col within [T,3D] row
    if (c4 >= 256 && c4 < 512) { v0 *= 8.f; v1 *= 8.f; v2 *= 8.f; v3 *= 8.f; }
  }
  ushort4 o;
  o.x = f2b(v0); o.y = f2b(v1); o.z = f2b(v2); o.w = f2b(v3);
  ((ushort4*)out)[i] = o;
}

// ----- fused: x2 = resid + bias + sum(4 partials); h2 = LN(x2) -------------
__global__ __launch_bounds__(256) void reduce4_ln(const unsigned short* __restrict__ p,
    const float* __restrict__ bias, const float* __restrict__ resid,
    const float* __restrict__ lnw, const float* __restrict__ lnb,
    float* __restrict__ x2, unsigned short* __restrict__ hout) {
  int row = blockIdx.x;
  int i = row * 256 + threadIdx.x;             // float4 index into [T,D]
  float4 r = ((const float4*)resid)[i];
  float4 bb = ((const float4*)bias)[threadIdx.x];
  float o0 = r.x + bb.x, o1 = r.y + bb.y, o2 = r.z + bb.z, o3 = r.w + bb.w;
#pragma unroll
  for (int z = 0; z < 4; ++z) {
    ushort4 pv = ((const ushort4*)(p + (size_t)z * TT * DD))[i];
    o0 += b2f(pv.x); o1 += b2f(pv.y); o2 += b2f(pv.z); o3 += b2f(pv.w);
  }
  float4 o; o.x = o0; o.y = o1; o.z = o2; o.w = o3;
  ((float4*)x2)[i] = o;
  float s  = o0 + o1 + o2 + o3;
  float ss = o0 * o0 + o1 * o1 + o2 * o2 + o3 * o3;
  for (int of = 32; of > 0; of >>= 1) {
    s  += __shfl_down(s, of);
    ss += __shfl_down(ss, of);
  }
  __shared__ float red[10];
  int lane = threadIdx.x & 63, wv = threadIdx.x >> 6;
  if (lane == 0) { red[wv] = s; red[4 + wv] = ss; }
  __syncthreads();
  if (threadIdx.x == 0) {
    float S  = red[0] + red[1] + red[2] + red[3];
    float SS = red[4] + red[5] + red[6] + red[7];
    float mu  = S * (1.0f / DD);
    float var = SS * (1.0f / DD) - mu * mu;
    red[8] = mu;
    red[9] = rsqrtf(var + 1e-5f);
  }
  __syncthreads();
  float mu = red[8], inv = red[9];
  float4 wv4 = ((const float4*)lnw)[threadIdx.x];
  float4 bv4 = ((const float4*)lnb)[threadIdx.x];
  ushort4 o4;
  o4.x = f2b((o0 - mu) * inv * wv4.x + bv4.x);
  o4.y = f2b((o1 - mu) * inv * wv4.y + bv4.y);
  o4.z = f2b((o2 - mu) * inv * wv4.z + bv4.z);
  o4.w = f2b((o3 - mu) * inv * wv4.w + bv4.w);
  ((ushort4*)(hout + (size_t)row * DD))[threadIdx.x] = o4;
}

// ---------------- reduce: 4+4 bf16 partials + bias + fp32 resid -> fp32 -----
__global__ __launch_bounds__(256) void reduce8(const unsigned short* __restrict__ pA,
    const unsigned short* __restrict__ pB, const float* __restrict__ bias,
    const float* __restrict__ resid, float* __restrict__ out) {
  int i = blockIdx.x * 256 + threadIdx.x;
  float4 r = ((const float4*)resid)[i];
  float4 bb = ((const float4*)bias)[i & (DD / 4 - 1)];
  float o0 = r.x + bb.x, o1 = r.y + bb.y, o2 = r.z + bb.z, o3 = r.w + bb.w;
#pragma unroll
  for (int z = 0; z < 4; ++z) {
    ushort4 pv = ((const ushort4*)(pA + (size_t)z * TT * DD))[i];
    o0 += b2f(pv.x); o1 += b2f(pv.y); o2 += b2f(pv.z); o3 += b2f(pv.w);
    ushort4 qv = ((const ushort4*)(pB + (size_t)z * TT * DD))[i];
    o0 += b2f(qv.x); o1 += b2f(qv.y); o2 += b2f(qv.z); o3 += b2f(qv.w);
  }
  float4 o; o.x = o0; o.y = o1; o.z = o2; o.w = o3;
  ((float4*)out)[i] = o;
}

// ---------------- V transpose: kqz V-section (head-contig) -> Vt[H][DH][T] --
__global__ __launch_bounds__(256) void transpose_v(const unsigned short* __restrict__ kqz,
    unsigned short* __restrict__ Vt) {
  const int h = blockIdx.y;
  const int t0 = blockIdx.x * 64;
  __shared__ unsigned short Vs[64][65];
  for (int idx = threadIdx.x; idx < 4096; idx += 256) {
    int t = idx >> 6, d = idx & 63;
    Vs[t][d] = kqz[(size_t)(t0 + t) * (3 * DD) + 2 * DD + h * 64 + d];
  }
  __syncthreads();
  for (int idx = threadIdx.x; idx < 4096; idx += 256) {
    int d = idx >> 6, t = idx & 63;
    Vt[(size_t)(h * DHD + d) * TT + t0 + t] = Vs[t][d];
  }
}

// ---------------- MFMA flash attention v7: 4-way KV-split, 48KB LDS, 3/CU ---
// 2048 blocks = 8 xcd x 256 items; item = (quarter, head_slot, qb). Each
// quarter processes KV-tile range [(c*NT)>>2, ((c+1)*NT)>>2) with its own
// online-softmax state; writes NORMALIZED partial O + (m,l). Quarter 3 is
// always nonempty and owns the diagonal tile. LPT order (big qb first).
// LDS 48KB: K single buf [0,16K), V single buf [16K,32K), P [32K,48K)
// -> 3 blocks/CU (occupancy beats in-block pipelining: R8 lesson; R11/R12
// showed deeper in-block prefetch is null at 2/CU).
__global__ __launch_bounds__(256) void attn6(
    const unsigned short* __restrict__ kqz,  // [T,3D] bf16: K | Q(x8) | V head-contig
    const unsigned short* __restrict__ Vt,   // [H,DH,T] bf16
    unsigned short* __restrict__ hvA,        // chunks 0,1: 2 x [T,D] bf16
    unsigned short* __restrict__ hvB,        // chunks 2,3: 2 x [T,D] bf16
    float2* __restrict__ mlarr) {            // [4*NH*TT] (m, l)
  const int bid = blockIdx.x;
  const int xcd = bid & 7, s = bid >> 3;     // s: 0..255
  const int quarter = s & 3;
  const int j = s >> 2;                      // 0..63
  const int hs = j & 1;
  const int qb = 31 - (j >> 1);              // size-descending (LPT)
  const int h  = xcd * 2 + hs;
  const int q0 = qb * 64;
  const int NT = (qb + 2) >> 1;              // total 128-key tiles for qb
  const int t0 = (quarter * NT) >> 2;
  const int t1 = ((quarter + 1) * NT) >> 2;

  const int tid = threadIdx.x;
  const int w = tid >> 6, l = tid & 63;
  const int l15 = l & 15, lhi = l >> 4;

  unsigned short* hvO = ((quarter & 2) ? hvB : hvA) + (size_t)(quarter & 1) * TT * DD;
  float2* mlO = mlarr + (size_t)(quarter * NH + h) * TT;

  if (t0 >= t1) {                            // empty quarter
#pragma unroll
    for (int r = 0; r < 4; ++r) {
      size_t orow = (size_t)(q0 + w * 16 + lhi * 4 + r) * DD + h * 64;
#pragma unroll
      for (int dt = 0; dt < 4; ++dt) hvO[orow + dt * 16 + l15] = 0;
    }
    if (lhi == 0) mlO[q0 + w * 16 + l15] = make_float2(-1e30f, 0.0f);
    return;
  }

  __shared__ char lds[49152];
  char* Ps = lds + 32768 + w * 4096;

  const char* kqzB = (const char*)kqz;
  const char* VhB  = (const char*)(Vt + (size_t)h * DHD * TT);
  const size_t KROW = 3 * DD * 2;            // 6144 B
  const size_t VROW = TT * 2;                // 4096 B

  const unsigned short* Qb = kqz + (size_t)(q0 + w * 16 + l15) * (3 * DD) + DD + h * 64;
  short8 qf0 = *(const short8*)(Qb + lhi * 8);
  short8 qf1 = *(const short8*)(Qb + 32 + lhi * 8);

  f32x4 oacc[4] = {};
  float m = -1e30f, lsum = 0.0f;

  const int kr8 = l >> 3;
  const int kcolb = ((l & 7) * 16) ^ (kr8 << 4);
  const int vg = l >> 4;
  const int vbase = (l & 15) * 16;
  const int kswz = (l15 & 7) << 4;           // K rows: 128B, 8 slots
  const int vpswz = (l15 & 15) << 4;         // V/P rows: 256B, 16 slots

  auto stageKV = [&](int kt2) {              // 8 GLDS per wave
    const int k0n = kt2 * 128;
    char* kb = lds + w * 4096;
    const char* ks = kqzB + (size_t)(k0n + w * 32 + kr8) * KROW + h * 128 + kcolb;
    GLDS16(ks,             kb);
    GLDS16(ks +  8 * KROW, kb + 1024);
    GLDS16(ks + 16 * KROW, kb + 2048);
    GLDS16(ks + 24 * KROW, kb + 3072);
    char* vb = lds + 16384 + w * 4096;
    const char* vs = VhB + (size_t)(w * 16 + vg) * VROW + (size_t)k0n * 2;
    GLDS16(vs +             (vbase ^ ((vg +  0) << 4)), vb);
    GLDS16(vs +  4 * VROW + (vbase ^ ((vg +  4) << 4)), vb + 1024);
    GLDS16(vs +  8 * VROW + (vbase ^ ((vg +  8) << 4)), vb + 2048);
    GLDS16(vs + 12 * VROW + (vbase ^ ((vg + 12) << 4)), vb + 3072);
  };

  for (int kt = t0; kt < t1; ++kt) {
    const int k0 = kt * 128;
    stageKV(kt);
    __builtin_amdgcn_sched_barrier(0);
    asm volatile("s_waitcnt vmcnt(0)" ::: "memory");
    __builtin_amdgcn_s_barrier();            // all waves' loads landed
    __builtin_amdgcn_sched_barrier(0);

    const char* Kb = lds;
    const char* Vb = lds + 16384;

    // ---- S^T = K Q^T: sacc[nt][r] = S[key=k0+nt*16+lhi*4+r][q=l15] ----
    f32x4 sacc[8] = {};
    __builtin_amdgcn_s_setprio(1);
#pragma unroll
    for (int nt = 0; nt < 8; ++nt) {
      const char* rp = Kb + (nt * 16 + l15) * 128;
      short8 kb0 = *(const short8*)(rp + ((lhi * 16) ^ kswz));
      short8 kb1 = *(const short8*)(rp + ((64 + lhi * 16) ^ kswz));
      sacc[nt] = MFMA16(kb0, qf0, sacc[nt]);
      sacc[nt] = MFMA16(kb1, qf1, sacc[nt]);
    }
    __builtin_amdgcn_s_setprio(0);

    if (kt == NT - 1) {                      // global diagonal tile
      const int qq = q0 + w * 16 + l15;
#pragma unroll
      for (int nt = 0; nt < 8; ++nt)
#pragma unroll
        for (int r = 0; r < 4; ++r)
          if (k0 + nt * 16 + lhi * 4 + r > qq) sacc[nt][r] = -1e30f;
    }

    // ---- online softmax (q=l15; reduce 32 regs + lhi groups) ----
    float tmax = -1e30f;
#pragma unroll
    for (int nt = 0; nt < 8; ++nt)
#pragma unroll
      for (int r = 0; r < 4; ++r) tmax = fmaxf(tmax, sacc[nt][r]);
    tmax = fmaxf(tmax, __shfl_xor(tmax, 16));
    tmax = fmaxf(tmax, __shfl_xor(tmax, 32));
    float mnew = fmaxf(m, tmax);
    float al = __expf(m - mnew);
    m = mnew;
    float ssum = 0.0f;
#pragma unroll
    for (int nt = 0; nt < 8; ++nt)
#pragma unroll
      for (int r = 0; r < 4; ++r) {
        float p = __expf(sacc[nt][r] - mnew);
        sacc[nt][r] = p;
        ssum += p;
      }
    ssum += __shfl_xor(ssum, 16);
    ssum += __shfl_xor(ssum, 32);
    lsum = lsum * al + ssum;

    // ---- P -> per-wave LDS (rows q=l15, 256B, 16-slot swizzle) ----
    {
      char* pp = Ps + l15 * 256;
#pragma unroll
      for (int nt = 0; nt < 8; ++nt) {
        uint2 pk;
        pk.x = (unsigned)f2b(sacc[nt][0]) | ((unsigned)f2b(sacc[nt][1]) << 16);
        pk.y = (unsigned)f2b(sacc[nt][2]) | ((unsigned)f2b(sacc[nt][3]) << 16);
        *(uint2*)(pp + ((nt * 32 + lhi * 8) ^ vpswz)) = pk;
      }
    }

    // ---- rescale O (rows q = lhi*4+r) ----
    float alr[4];
#pragma unroll
    for (int r = 0; r < 4; ++r) alr[r] = __shfl(al, (l & 48) | (lhi * 4 + r));
#pragma unroll
    for (int dt = 0; dt < 4; ++dt)
#pragma unroll
      for (int r = 0; r < 4; ++r) oacc[dt][r] *= alr[r];

    // ---- O += P V ----
    const char* pr = Ps + l15 * 256;
    short8 pa[4];
#pragma unroll
    for (int kc = 0; kc < 4; ++kc)
      pa[kc] = *(const short8*)(pr + ((kc * 64 + lhi * 16) ^ vpswz));
    __builtin_amdgcn_s_setprio(1);
#pragma unroll
    for (int dt = 0; dt < 4; ++dt) {
      const char* vr = Vb + (dt * 16 + l15) * 256;
#pragma unroll
      for (int kc = 0; kc < 4; ++kc) {
        short8 vbf = *(const short8*)(vr + ((kc * 64 + lhi * 16) ^ vpswz));
        oacc[dt] = MFMA16(pa[kc], vbf, oacc[dt]);
      }
    }
    __builtin_amdgcn_s_setprio(0);

    __builtin_amdgcn_sched_barrier(0);
    __builtin_amdgcn_s_barrier();            // readers done before next stage
  }

  // ---- epilogue: normalized partial O + (m, l) ----
  float lr4[4];
#pragma unroll
  for (int r = 0; r < 4; ++r) {
    float lv = __shfl(lsum, (l & 48) | (lhi * 4 + r));
    lr4[r] = 1.0f / lv;
  }
#pragma unroll
  for (int r = 0; r < 4; ++r) {
    size_t orow = (size_t)(q0 + w * 16 + lhi * 4 + r) * DD + h * 64;
#pragma unroll
    for (int dt = 0; dt < 4; ++dt)
      hvO[orow + dt * 16 + l15] = f2b(oacc[dt][r] * lr4[r]);
  }
  if (lhi == 0) mlO[q0 + w * 16 + l15] = make_float2(m, lsum);
}

// ---------------- merge the four KV-quarters -> hv ----------------
__global__ __launch_bounds__(256) void merge_attn4(
    const unsigned short* __restrict__ hvA, const unsigned short* __restrict__ hvB,
    const float2* __restrict__ mlarr, unsigned short* __restrict__ hv) {
  int row = blockIdx.x;
  int t = threadIdx.x;                       // col4 index, D/4 = 256
  int h = t >> 4;
  float2 ml0 = mlarr[(size_t)(0 * NH + h) * TT + row];
  float2 ml1 = mlarr[(size_t)(1 * NH + h) * TT + row];
  float2 ml2 = mlarr[(size_t)(2 * NH + h) * TT + row];
  float2 ml3 = mlarr[(size_t)(3 * NH + h) * TT + row];
  float M = fmaxf(fmaxf(ml0.x, ml1.x), fmaxf(ml2.x, ml3.x));
  float w0 = ml0.y * __expf(ml0.x - M);
  float w1 = ml1.y * __expf(ml1.x - M);
  float w2 = ml2.y * __expf(ml2.x - M);
  float w3 = ml3.y * __expf(ml3.x - M);
  float inv = 1.0f / (w0 + w1 + w2 + w3);
  w0 *= inv; w1 *= inv; w2 *= inv; w3 *= inv;
  size_t i = (size_t)row * 256 + t;
  ushort4 a = ((const ushort4*)hvA)[i];
  ushort4 b = ((const ushort4*)(hvA + (size_t)TT * DD))[i];
  ushort4 c = ((const ushort4*)hvB)[i];
  ushort4 d = ((const ushort4*)(hvB + (size_t)TT * DD))[i];
  ushort4 o;
  o.x = f2b(w0 * b2f(a.x) + w1 * b2f(b.x) + w2 * b2f(c.x) + w3 * b2f(d.x));
  o.y = f2b(w0 * b2f(a.y) + w1 * b2f(b.y) + w2 * b2f(c.y) + w3 * b2f(d.y));
  o.z = f2b(w0 * b2f(a.z) + w1 * b2f(b.z) + w2 * b2f(c.z) + w3 * b2f(d.z));
  o.w = f2b(w0 * b2f(a.w) + w1 * b2f(b.w) + w2 * b2f(c.w) + w3 * b2f(d.w));
  ((ushort4*)hv)[i] = o;
}

// ---------------- launch ----------------
extern "C" void kernel_launch(void* const* d_in, const int* in_sizes, int n_in,
                              void* d_out, int out_size, void* d_ws, size_t ws_size,
                              hipStream_t stream) {
  const float* x     = (const float*)d_in[0];
  const float* w_kqv = (const float*)d_in[1];
  const float* b_kqv = (const float*)d_in[2];
  const float* w_o   = (const float*)d_in[3];
  const float* b_o   = (const float*)d_in[4];
  const float* ln1_w = (const float*)d_in[5];
  const float* ln1_b = (const float*)d_in[6];
  const float* ln2_w = (const float*)d_in[7];
  const float* ln2_b = (const float*)d_in[8];
  const float* w_up  = (const float*)d_in[9];
  const float* b_up  = (const float*)d_in[10];
  const float* w_dn  = (const float*)d_in[11];
  const float* b_dn  = (const float*)d_in[12];
  float* out = (float*)d_out;

  char* W = (char*)d_ws;
  unsigned short* wkqv_b = (unsigned short*)(W);                 // [0,6) MiB (permuted)
  unsigned short* wo_b   = (unsigned short*)(W + 6291456);       // [6,8)
  unsigned short* wup_b  = (unsigned short*)(W + 8388608);       // [8,16)
  unsigned short* wdn_b  = (unsigned short*)(W + 16777216);      // [16,24)
  unsigned short* h_b    = (unsigned short*)(W + 25165824);      // [24,28)
  float2*         mlarr  = (float2*)(W + 25165824);              // [24,25) h_b dead in attn
  unsigned short* rA     = (unsigned short*)(W + 29360128);      // [28,44)
  unsigned short* rB     = (unsigned short*)(W + 46137344);      // [44,60)
  unsigned short* hvq01  = (unsigned short*)(W + 46137344);      // [44,52) chunks 0,1
  unsigned short* Vtg    = (unsigned short*)(W + 54525952);      // [52,56)
  unsigned short* hv_b   = (unsigned short*)(W + 58720256);      // [56,60)
  float*          x2     = (float*)(W + 62914560);               // [60,68)
  unsigned short* hvq23  = (unsigned short*)(W + 62914560);      // [60,68) chunks 2,3 (x2 dead)
  unsigned short* pB2    = (unsigned short*)(W);                 // [0,16) dead weights at down time

  // weight convert (w_kqv head-permuted)
  f2b4_kernel<<<3145728 / 256, 256, 0, stream>>>(w_kqv, w_o, w_up, w_dn, wkqv_b);

  // 1. h = LN1(x)
  ln_kernel<<<TT, 256, 0, stream>>>(x, ln1_w, ln1_b, h_b);
  // 2. kqv split-2 -> partials rA/rB; grid 768 = 8*(3x32)
  gemm6<<<768, 256, 0, stream>>>(h_b, wkqv_b, rA, rB,
      TT, 3 * DD, DD, DD / 2, 3, 32, 1);
  //    kqz = rA+rB+b_kqv, Q-section x8 (bf16, in-place over rA)
  reduce2b<2><<<TT * 3 * DD / 4 / 256, 256, 0, stream>>>(
      rA, rB, b_kqv, rA, 3 * DD / 4);
  // 3. V transpose (coalesced reads from kqz)
  transpose_v<<<dim3(TT / 64, NH), 256, 0, stream>>>(rA, Vtg);
  // 4. attention 4-way KV-split (2048 blocks) + merge -> hv bf16
  attn6<<<2048, 256, 0, stream>>>(rA, Vtg, hvq01, hvq23, mlarr);
  merge_attn4<<<TT, 256, 0, stream>>>(hvq01, hvq23, mlarr, hv_b);
  // 5. proj split-4 -> partials rA (kqz dead); grid 512 = 8*(1x64)
  gemm6<<<512, 256, 0, stream>>>(hv_b, wo_b, rA, rA,
      TT, DD, DD, DD / 4, 1, 64, 4);
  //    x2 = x + b_o + sum(p0..3);  h2 = LN2(x2)   (fused)
  reduce4_ln<<<TT, 256, 0, stream>>>(rA, b_o, x, ln2_w, ln2_b, x2, h_b);
  // 7. up split-2 -> partials rA/rB; grid 1024 = 8*(4x32)
  gemm6<<<1024, 256, 0, stream>>>(h_b, wup_b, rA, rB,
      TT, DFF, DD, DD / 2, 4, 32, 1);
  //    z1 = gelu(rA+rB+b_up) (bf16, in-place over rA)
  reduce2b<1><<<TT * DFF / 4 / 256, 256, 0, stream>>>(
      rA, rB, b_up, rA, DFF / 4);
  // 8. down split-8 -> partials rB (4x) + pB2 (4x); grid 1024 = 8*(1x128)
  gemm6<<<1024, 256, 0, stream>>>(rA, wdn_b, rB, pB2,
      TT, DD, DFF, DFF / 8, 1, 128, 4);
  //    out = x2 + b_dn + sum(all 8 partials)
  reduce8<<<TT * DD / 4 / 256, 256, 0, stream>>>(rB, pB2, b_dn, x2, out);
}

// Round 14
// 179.497 us; speedup vs baseline: 1.0558x; 1.0558x over previous
//
#include <hip/hip_runtime.h>
#include <math.h>

#define TT 2048
#define DD 1024
#define NH 16
#define DHD 64
#define DFF 4096

typedef __attribute__((ext_vector_type(8))) short short8;
typedef __attribute__((ext_vector_type(4))) float f32x4;

#define MFMA16(a, b, c) __builtin_amdgcn_mfma_f32_16x16x32_bf16(a, b, c, 0, 0, 0)
#define GLDS16(gp, lp) __builtin_amdgcn_global_load_lds( \
    (const __attribute__((address_space(1))) void*)(gp), \
    (__attribute__((address_space(3))) void*)(lp), 16, 0, 0)

static __device__ __forceinline__ unsigned short f2b(float f) {
  unsigned u = __builtin_bit_cast(unsigned, f);
  u = u + 0x7fffu + ((u >> 16) & 1u);
  return (unsigned short)(u >> 16);
}
static __device__ __forceinline__ float b2f(unsigned short b) {
  return __builtin_bit_cast(float, (unsigned)b << 16);
}

// ---------------- fp32 -> bf16 convert; w_kqv rows PERMUTED head-contiguous -
__global__ __launch_bounds__(256) void f2b4_kernel(const float* __restrict__ s0,
    const float* __restrict__ s1, const float* __restrict__ s2,
    const float* __restrict__ s3, unsigned short* __restrict__ out) {
  int i = blockIdx.x * 256 + threadIdx.x;
  float4 v;
  if (i < 786432) {
    int row = i >> 8, kk = i & 255;
    int sec = row >> 10, wi = row & 1023;
    int src = (sec << 10) + ((wi & 63) << 4) + (wi >> 6);
    v = ((const float4*)s0)[(src << 8) + kk];
  } else if (i < 1048576) {
    v = ((const float4*)s1)[i - 786432];
  } else if (i < 2097152) {
    v = ((const float4*)s2)[i - 1048576];
  } else {
    v = ((const float4*)s3)[i - 2097152];
  }
  ushort4 o;
  o.x = f2b(v.x); o.y = f2b(v.y); o.z = f2b(v.z); o.w = f2b(v.w);
  ((ushort4*)out)[i] = o;
}

// ---------------- LayerNorm (fp32 in, bf16 out) ----------------
__global__ __launch_bounds__(256) void ln_kernel(const float* __restrict__ x,
    const float* __restrict__ w, const float* __restrict__ b,
    unsigned short* __restrict__ out) {
  int row = blockIdx.x;
  const float4* xr = (const float4*)(x + (size_t)row * DD);
  float4 v = xr[threadIdx.x];
  float s  = v.x + v.y + v.z + v.w;
  float ss = v.x * v.x + v.y * v.y + v.z * v.z + v.w * v.w;
  for (int o = 32; o > 0; o >>= 1) {
    s  += __shfl_down(s, o);
    ss += __shfl_down(ss, o);
  }
  __shared__ float red[10];
  int lane = threadIdx.x & 63, wv = threadIdx.x >> 6;
  if (lane == 0) { red[wv] = s; red[4 + wv] = ss; }
  __syncthreads();
  if (threadIdx.x == 0) {
    float S  = red[0] + red[1] + red[2] + red[3];
    float SS = red[4] + red[5] + red[6] + red[7];
    float mu  = S * (1.0f / DD);
    float var = SS * (1.0f / DD) - mu * mu;
    red[8] = mu;
    red[9] = rsqrtf(var + 1e-5f);
  }
  __syncthreads();
  float mu = red[8], inv = red[9];
  float4 wv4 = ((const float4*)w)[threadIdx.x];
  float4 bv4 = ((const float4*)b)[threadIdx.x];
  ushort4 o4;
  o4.x = f2b((v.x - mu) * inv * wv4.x + bv4.x);
  o4.y = f2b((v.y - mu) * inv * wv4.y + bv4.y);
  o4.z = f2b((v.z - mu) * inv * wv4.z + bv4.z);
  o4.w = f2b((v.w - mu) * inv * wv4.w + bv4.w);
  ((ushort4*)(out + (size_t)row * DD))[threadIdx.x] = o4;
}

// ---------------- bf16 MFMA GEMM v6 (proven): 128x128, BK=32, 32KB LDS ------
// XCD chunk remap: xcd owns a CX x CY chunk of (x, y + GYM*z) tile space,
// chosen so the per-XCD A-panel + B-panel fits the 4MB L2 (R14 fix: the
// old CX/CY streamed ALL of A through each XCD's L2).
__global__ __launch_bounds__(256, 4) void gemm6(
    const unsigned short* __restrict__ A,   // [M,K] bf16
    const unsigned short* __restrict__ Bw,  // [N,K] bf16
    unsigned short* __restrict__ Cp,        // partials, bz < SPLITA
    unsigned short* __restrict__ Cp2,       // partials, bz >= SPLITA
    int M, int N, int K, int KS, int CX, int CY, int SPLITA) {
  __shared__ char lds[32768];
  const int tid = threadIdx.x;
  const int w = tid >> 6, l = tid & 63;
  const int l15 = l & 15, lhi = l >> 4;

  const int GX = N >> 7, GYM = M >> 7;
  const int xcd = blockIdx.x & 7, s = blockIdx.x >> 3;
  const int ncx = GX / CX;
  const int bx = (xcd % ncx) * CX + (s % CX);
  const int yz = (xcd / ncx) * CY + (s / CX);
  const int by = yz % GYM, bz = yz / GYM;

  const int row0 = by << 7, col0 = bx << 7;
  const int kbeg = bz * KS;
  const int wm = (w >> 1) * 64, wn = (w & 1) * 64;

  f32x4 acc[4][4] = {};

  const int srow = w * 32 + (l >> 2);
  const int scol = (l & 3) * 16;
  const char* aS = (const char*)A + ((size_t)(row0 + srow) * K + kbeg) * 2 + scol;
  const char* bS = (const char*)Bw + ((size_t)(col0 + srow) * K + kbeg) * 2 + scol;
  const size_t r16 = (size_t)K * 32;
  const int aO = w * 2048, bO = 8192 + w * 2048;
  const int NT = KS >> 5;

  auto STAGE = [&](int t) {
    char* base = lds + (t & 1) * 16384;
    const char* a = aS + (size_t)t * 64;
    const char* b = bS + (size_t)t * 64;
    GLDS16(a,       base + aO);
    GLDS16(a + r16, base + aO + 1024);
    GLDS16(b,       base + bO);
    GLDS16(b + r16, base + bO + 1024);
  };
  auto COMPUTE = [&](int t) {
    const char* Ab = lds + (t & 1) * 16384;
    const char* Bb = Ab + 8192;
    short8 af[4], bf[4];
#pragma unroll
    for (int mi = 0; mi < 4; ++mi)
      af[mi] = *(const short8*)(Ab + (wm + mi * 16 + l15) * 64 + lhi * 16);
#pragma unroll
    for (int ni = 0; ni < 4; ++ni)
      bf[ni] = *(const short8*)(Bb + (wn + ni * 16 + l15) * 64 + lhi * 16);
    __builtin_amdgcn_s_setprio(1);
#pragma unroll
    for (int mi = 0; mi < 4; ++mi)
#pragma unroll
      for (int ni = 0; ni < 4; ++ni)
        acc[mi][ni] = MFMA16(af[mi], bf[ni], acc[mi][ni]);
    __builtin_amdgcn_s_setprio(0);
  };

  STAGE(0);
  for (int t = 0; t < NT; ++t) {
    if (t + 1 < NT) STAGE(t + 1);
    __builtin_amdgcn_sched_barrier(0);
    if (t + 1 < NT) asm volatile("s_waitcnt vmcnt(4)" ::: "memory");
    else            asm volatile("s_waitcnt vmcnt(0)" ::: "memory");
    __builtin_amdgcn_s_barrier();
    __builtin_amdgcn_sched_barrier(0);
    COMPUTE(t);
    __builtin_amdgcn_sched_barrier(0);
    __builtin_amdgcn_s_barrier();
  }

  unsigned short* base;
  size_t off;
  if (bz < SPLITA) { base = Cp;  off = (size_t)bz * M * N; }
  else             { base = Cp2; off = (size_t)(bz - SPLITA) * M * N; }
#pragma unroll
  for (int mi = 0; mi < 4; ++mi)
#pragma unroll
    for (int r = 0; r < 4; ++r) {
      size_t row = (size_t)(row0 + wm + mi * 16 + lhi * 4 + r);
#pragma unroll
      for (int ni = 0; ni < 4; ++ni)
        base[off + row * N + col0 + wn + ni * 16 + l15] = f2b(acc[mi][ni][r]);
    }
}

// ------- reduce: 2 bf16 partials + bias; MODE 0=plain,1=gelu,2=kqv(Q x8) ----
template<int MODE>
__global__ __launch_bounds__(256) void reduce2b(const unsigned short* __restrict__ p0,
    const unsigned short* __restrict__ p1, const float* __restrict__ bias,
    unsigned short* __restrict__ out, int n4) {
  int i = blockIdx.x * 256 + threadIdx.x;
  ushort4 a = ((const ushort4*)p0)[i];
  ushort4 b = ((const ushort4*)p1)[i];
  float4 bb = ((const float4*)bias)[i % n4];
  float v0 = b2f(a.x) + b2f(b.x) + bb.x;
  float v1 = b2f(a.y) + b2f(b.y) + bb.y;
  float v2 = b2f(a.z) + b2f(b.z) + bb.z;
  float v3 = b2f(a.w) + b2f(b.w) + bb.w;
  if (MODE == 1) {
    const float c = 0.7978845608028654f;
    v0 = 0.5f * v0 * (1.0f + tanhf(c * (v0 + 0.044715f * v0 * v0 * v0)));
    v1 = 0.5f * v1 * (1.0f + tanhf(c * (v1 + 0.044715f * v1 * v1 * v1)));
    v2 = 0.5f * v2 * (1.0f + tanhf(c * (v2 + 0.044715f * v2 * v2 * v2)));
    v3 = 0.5f * v3 * (1.0f + tanhf(c * (v3 + 0.044715f * v3 * v3 * v3)));
  }
  if (MODE == 2) {
    int c4 = i % 768;                       // float4-col within [T,3D] row
    if (c4 >= 256 && c4 < 512) { v0 *= 8.f; v1 *= 8.f; v2 *= 8.f; v3 *= 8.f; }
  }
  ushort4 o;
  o.x = f2b(v0); o.y = f2b(v1); o.z = f2b(v2); o.w = f2b(v3);
  ((ushort4*)out)[i] = o;
}

// ----- fused: x2 = resid + bias + sum(4 partials); h2 = LN(x2) -------------
__global__ __launch_bounds__(256) void reduce4_ln(const unsigned short* __restrict__ p,
    const float* __restrict__ bias, const float* __restrict__ resid,
    const float* __restrict__ lnw, const float* __restrict__ lnb,
    float* __restrict__ x2, unsigned short* __restrict__ hout) {
  int row = blockIdx.x;
  int i = row * 256 + threadIdx.x;             // float4 index into [T,D]
  float4 r = ((const float4*)resid)[i];
  float4 bb = ((const float4*)bias)[threadIdx.x];
  float o0 = r.x + bb.x, o1 = r.y + bb.y, o2 = r.z + bb.z, o3 = r.w + bb.w;
#pragma unroll
  for (int z = 0; z < 4; ++z) {
    ushort4 pv = ((const ushort4*)(p + (size_t)z * TT * DD))[i];
    o0 += b2f(pv.x); o1 += b2f(pv.y); o2 += b2f(pv.z); o3 += b2f(pv.w);
  }
  float4 o; o.x = o0; o.y = o1; o.z = o2; o.w = o3;
  ((float4*)x2)[i] = o;
  float s  = o0 + o1 + o2 + o3;
  float ss = o0 * o0 + o1 * o1 + o2 * o2 + o3 * o3;
  for (int of = 32; of > 0; of >>= 1) {
    s  += __shfl_down(s, of);
    ss += __shfl_down(ss, of);
  }
  __shared__ float red[10];
  int lane = threadIdx.x & 63, wv = threadIdx.x >> 6;
  if (lane == 0) { red[wv] = s; red[4 + wv] = ss; }
  __syncthreads();
  if (threadIdx.x == 0) {
    float S  = red[0] + red[1] + red[2] + red[3];
    float SS = red[4] + red[5] + red[6] + red[7];
    float mu  = S * (1.0f / DD);
    float var = SS * (1.0f / DD) - mu * mu;
    red[8] = mu;
    red[9] = rsqrtf(var + 1e-5f);
  }
  __syncthreads();
  float mu = red[8], inv = red[9];
  float4 wv4 = ((const float4*)lnw)[threadIdx.x];
  float4 bv4 = ((const float4*)lnb)[threadIdx.x];
  ushort4 o4;
  o4.x = f2b((o0 - mu) * inv * wv4.x + bv4.x);
  o4.y = f2b((o1 - mu) * inv * wv4.y + bv4.y);
  o4.z = f2b((o2 - mu) * inv * wv4.z + bv4.z);
  o4.w = f2b((o3 - mu) * inv * wv4.w + bv4.w);
  ((ushort4*)(hout + (size_t)row * DD))[threadIdx.x] = o4;
}

// ---------------- reduce: 4+4 bf16 partials + bias + fp32 resid -> fp32 -----
__global__ __launch_bounds__(256) void reduce8(const unsigned short* __restrict__ pA,
    const unsigned short* __restrict__ pB, const float* __restrict__ bias,
    const float* __restrict__ resid, float* __restrict__ out) {
  int i = blockIdx.x * 256 + threadIdx.x;
  float4 r = ((const float4*)resid)[i];
  float4 bb = ((const float4*)bias)[i & (DD / 4 - 1)];
  float o0 = r.x + bb.x, o1 = r.y + bb.y, o2 = r.z + bb.z, o3 = r.w + bb.w;
#pragma unroll
  for (int z = 0; z < 4; ++z) {
    ushort4 pv = ((const ushort4*)(pA + (size_t)z * TT * DD))[i];
    o0 += b2f(pv.x); o1 += b2f(pv.y); o2 += b2f(pv.z); o3 += b2f(pv.w);
    ushort4 qv = ((const ushort4*)(pB + (size_t)z * TT * DD))[i];
    o0 += b2f(qv.x); o1 += b2f(qv.y); o2 += b2f(qv.z); o3 += b2f(qv.w);
  }
  float4 o; o.x = o0; o.y = o1; o.z = o2; o.w = o3;
  ((float4*)out)[i] = o;
}

// ---------------- V transpose: kqz V-section (head-contig) -> Vt[H][DH][T] --
__global__ __launch_bounds__(256) void transpose_v(const unsigned short* __restrict__ kqz,
    unsigned short* __restrict__ Vt) {
  const int h = blockIdx.y;
  const int t0 = blockIdx.x * 64;
  __shared__ unsigned short Vs[64][65];
  for (int idx = threadIdx.x; idx < 4096; idx += 256) {
    int t = idx >> 6, d = idx & 63;
    Vs[t][d] = kqz[(size_t)(t0 + t) * (3 * DD) + 2 * DD + h * 64 + d];
  }
  __syncthreads();
  for (int idx = threadIdx.x; idx < 4096; idx += 256) {
    int d = idx >> 6, t = idx & 63;
    Vt[(size_t)(h * DHD + d) * TT + t0 + t] = Vs[t][d];
  }
}

// ---------------- MFMA flash attention (R11 attn4, best measured) -----------
// grid 512, snake-balanced (CU j: qb=31-j + qb=j). KVBLK=128.
// LDS 80KB: K dbuf [0,32K), V dbuf [32K,64K), P per-wave [64K,80K) -> 2/CU.
// Per tile: ONE vmcnt(8) (K/V(kt) issued 2 tiles earlier) + 2 barriers.
__global__ __launch_bounds__(256) void attn4(
    const unsigned short* __restrict__ kqz,  // [T,3D] bf16: K | Q(x8) | V head-contig
    const unsigned short* __restrict__ Vt,   // [H,DH,T] bf16
    unsigned short* __restrict__ hv) {       // [T,D] bf16, head-slow cols
  const int bid = blockIdx.x;
  const int xcd = bid & 7, s = bid >> 3;
  const int hs = s >> 5, j = s & 31;
  const int qb = hs ? j : 31 - j;            // snake: balanced pairs per CU
  const int h  = xcd * 2 + hs;
  const int q0 = qb * 64;
  const int tid = threadIdx.x;
  const int w = tid >> 6, l = tid & 63;
  const int l15 = l & 15, lhi = l >> 4;

  __shared__ char lds[81920];
  char* Ps = lds + 65536 + w * 4096;         // per-wave 16 q x 128 k (256B rows)

  const char* kqzB = (const char*)kqz;
  const char* VhB  = (const char*)(Vt + (size_t)h * DHD * TT);
  const size_t KROW = 3 * DD * 2;            // 6144 B
  const size_t VROW = TT * 2;                // 4096 B

  const unsigned short* Qb = kqz + (size_t)(q0 + w * 16 + l15) * (3 * DD) + DD + h * 64;
  short8 qf0 = *(const short8*)(Qb + lhi * 8);
  short8 qf1 = *(const short8*)(Qb + 32 + lhi * 8);

  f32x4 oacc[4] = {};
  float m = -1e30f, lsum = 0.0f;

  const int kr8 = l >> 3;
  const int kcolb = ((l & 7) * 16) ^ (kr8 << 4);
  const int vg = l >> 4;
  const int vbase = (l & 15) * 16;
  const int kswz = (l15 & 7) << 4;           // K rows: 128B, 8 slots
  const int vpswz = (l15 & 15) << 4;         // V/P rows: 256B, 16 slots

  auto stageKV = [&](int kt2) {              // 8 GLDS per wave
    const int buf = kt2 & 1;
    const int k0n = kt2 * 128;
    char* kb = lds + buf * 16384 + w * 4096;
    const char* ks = kqzB + (size_t)(k0n + w * 32 + kr8) * KROW + h * 128 + kcolb;
    GLDS16(ks,             kb);
    GLDS16(ks +  8 * KROW, kb + 1024);
    GLDS16(ks + 16 * KROW, kb + 2048);
    GLDS16(ks + 24 * KROW, kb + 3072);
    char* vb = lds + 32768 + buf * 16384 + w * 4096;
    const char* vs = VhB + (size_t)(w * 16 + vg) * VROW + (size_t)k0n * 2;
    GLDS16(vs +             (vbase ^ ((vg +  0) << 4)), vb);
    GLDS16(vs +  4 * VROW + (vbase ^ ((vg +  4) << 4)), vb + 1024);
    GLDS16(vs +  8 * VROW + (vbase ^ ((vg +  8) << 4)), vb + 2048);
    GLDS16(vs + 12 * VROW + (vbase ^ ((vg + 12) << 4)), vb + 3072);
  };

  const int NT = (qb + 2) >> 1;           // 128-key tiles
  stageKV(0);
  if (NT > 1) stageKV(1);

  for (int kt = 0; kt < NT; ++kt) {
    const int k0 = kt * 128;
    __builtin_amdgcn_sched_barrier(0);
    if (kt + 1 < NT) asm volatile("s_waitcnt vmcnt(8)" ::: "memory");  // K/V(kt)
    else             asm volatile("s_waitcnt vmcnt(0)" ::: "memory");
    __builtin_amdgcn_s_barrier();                       // loads visible to all
    __builtin_amdgcn_sched_barrier(0);

    const char* Kb = lds + (kt & 1) * 16384;
    const char* Vb = lds + 32768 + (kt & 1) * 16384;

    // ---- S^T = K Q^T: sacc[nt][r] = S[key=k0+nt*16+lhi*4+r][q=l15] ----
    f32x4 sacc[8] = {};
    __builtin_amdgcn_s_setprio(1);
#pragma unroll
    for (int nt = 0; nt < 8; ++nt) {
      const char* rp = Kb + (nt * 16 + l15) * 128;
      short8 kb0 = *(const short8*)(rp + ((lhi * 16) ^ kswz));
      short8 kb1 = *(const short8*)(rp + ((64 + lhi * 16) ^ kswz));
      sacc[nt] = MFMA16(kb0, qf0, sacc[nt]);
      sacc[nt] = MFMA16(kb1, qf1, sacc[nt]);
    }
    __builtin_amdgcn_s_setprio(0);

    if (kt == NT - 1) {                   // only the last tile can mask
      const int qq = q0 + w * 16 + l15;
#pragma unroll
      for (int nt = 0; nt < 8; ++nt)
#pragma unroll
        for (int r = 0; r < 4; ++r)
          if (k0 + nt * 16 + lhi * 4 + r > qq) sacc[nt][r] = -1e30f;
    }

    // ---- online softmax (q=l15; reduce 32 regs + lhi groups) ----
    float tmax = -1e30f;
#pragma unroll
    for (int nt = 0; nt < 8; ++nt)
#pragma unroll
      for (int r = 0; r < 4; ++r) tmax = fmaxf(tmax, sacc[nt][r]);
    tmax = fmaxf(tmax, __shfl_xor(tmax, 16));
    tmax = fmaxf(tmax, __shfl_xor(tmax, 32));
    float mnew = fmaxf(m, tmax);
    float al = __expf(m - mnew);
    m = mnew;
    float ssum = 0.0f;
#pragma unroll
    for (int nt = 0; nt < 8; ++nt)
#pragma unroll
      for (int r = 0; r < 4; ++r) {
        float p = __expf(sacc[nt][r] - mnew);
        sacc[nt][r] = p;
        ssum += p;
      }
    ssum += __shfl_xor(ssum, 16);
    ssum += __shfl_xor(ssum, 32);
    lsum = lsum * al + ssum;

    // ---- P -> per-wave LDS (rows q=l15, 256B, 16-slot swizzle; 8 x b64) ----
    {
      char* pp = Ps + l15 * 256;
#pragma unroll
      for (int nt = 0; nt < 8; ++nt) {
        uint2 pk;
        pk.x = (unsigned)f2b(sacc[nt][0]) | ((unsigned)f2b(sacc[nt][1]) << 16);
        pk.y = (unsigned)f2b(sacc[nt][2]) | ((unsigned)f2b(sacc[nt][3]) << 16);
        *(uint2*)(pp + ((nt * 32 + lhi * 8) ^ vpswz)) = pk;
      }
    }

    // ---- rescale O (rows q = lhi*4+r) ----
    float alr[4];
#pragma unroll
    for (int r = 0; r < 4; ++r) alr[r] = __shfl(al, (l & 48) | (lhi * 4 + r));
#pragma unroll
    for (int dt = 0; dt < 4; ++dt)
#pragma unroll
      for (int r = 0; r < 4; ++r) oacc[dt][r] *= alr[r];

    // ---- O += P V (128-key span: 4 k-chunks) ----
    const char* pr = Ps + l15 * 256;
    short8 pa[4];
#pragma unroll
    for (int kc = 0; kc < 4; ++kc)
      pa[kc] = *(const short8*)(pr + ((kc * 64 + lhi * 16) ^ vpswz));
    __builtin_amdgcn_s_setprio(1);
#pragma unroll
    for (int dt = 0; dt < 4; ++dt) {
      const char* vr = Vb + (dt * 16 + l15) * 256;
#pragma unroll
      for (int kc = 0; kc < 4; ++kc) {
        short8 vbf = *(const short8*)(vr + ((kc * 64 + lhi * 16) ^ vpswz));
        oacc[dt] = MFMA16(pa[kc], vbf, oacc[dt]);
      }
    }
    __builtin_amdgcn_s_setprio(0);

    __builtin_amdgcn_sched_barrier(0);
    __builtin_amdgcn_s_barrier();         // readers of buf (kt&1) done
    if (kt + 2 < NT) stageKV(kt + 2);     // overwrite buf (kt&1); lands in 2 tiles
  }

  float lr4[4];
#pragma unroll
  for (int r = 0; r < 4; ++r)
    lr4[r] = 1.0f / __shfl(lsum, (l & 48) | (lhi * 4 + r));
#pragma unroll
  for (int r = 0; r < 4; ++r) {
    size_t orow = (size_t)(q0 + w * 16 + lhi * 4 + r) * DD + h * 64;
#pragma unroll
    for (int dt = 0; dt < 4; ++dt)
      hv[orow + dt * 16 + l15] = f2b(oacc[dt][r] * lr4[r]);
  }
}

// ---------------- launch ----------------
extern "C" void kernel_launch(void* const* d_in, const int* in_sizes, int n_in,
                              void* d_out, int out_size, void* d_ws, size_t ws_size,
                              hipStream_t stream) {
  const float* x     = (const float*)d_in[0];
  const float* w_kqv = (const float*)d_in[1];
  const float* b_kqv = (const float*)d_in[2];
  const float* w_o   = (const float*)d_in[3];
  const float* b_o   = (const float*)d_in[4];
  const float* ln1_w = (const float*)d_in[5];
  const float* ln1_b = (const float*)d_in[6];
  const float* ln2_w = (const float*)d_in[7];
  const float* ln2_b = (const float*)d_in[8];
  const float* w_up  = (const float*)d_in[9];
  const float* b_up  = (const float*)d_in[10];
  const float* w_dn  = (const float*)d_in[11];
  const float* b_dn  = (const float*)d_in[12];
  float* out = (float*)d_out;

  char* W = (char*)d_ws;
  unsigned short* wkqv_b = (unsigned short*)(W);                 // [0,6) MiB (permuted)
  unsigned short* wo_b   = (unsigned short*)(W + 6291456);       // [6,8)
  unsigned short* wup_b  = (unsigned short*)(W + 8388608);       // [8,16)
  unsigned short* wdn_b  = (unsigned short*)(W + 16777216);      // [16,24)
  unsigned short* h_b    = (unsigned short*)(W + 25165824);      // [24,28)
  unsigned short* rA     = (unsigned short*)(W + 29360128);      // [28,44)
  unsigned short* rB     = (unsigned short*)(W + 46137344);      // [44,60)
  unsigned short* Vtg    = (unsigned short*)(W + 54525952);      // [52,56)
  unsigned short* hv_b   = (unsigned short*)(W + 58720256);      // [56,60)
  float*          x2     = (float*)(W + 62914560);               // [60,68)
  unsigned short* pB2    = (unsigned short*)(W);                 // [0,16) dead weights at down time

  // weight convert (w_kqv head-permuted)
  f2b4_kernel<<<3145728 / 256, 256, 0, stream>>>(w_kqv, w_o, w_up, w_dn, wkqv_b);

  // 1. h = LN1(x)
  ln_kernel<<<TT, 256, 0, stream>>>(x, ln1_w, ln1_b, h_b);
  // 2. kqv split-2 -> partials rA/rB; grid 768 = 8*(12x8); per-XCD 2.5MB L2
  gemm6<<<768, 256, 0, stream>>>(h_b, wkqv_b, rA, rB,
      TT, 3 * DD, DD, DD / 2, 12, 8, 1);
  //    kqz = rA+rB+b_kqv, Q-section x8 (bf16, in-place over rA)
  reduce2b<2><<<TT * 3 * DD / 4 / 256, 256, 0, stream>>>(
      rA, rB, b_kqv, rA, 3 * DD / 4);
  // 3. V transpose (coalesced reads from kqz)
  transpose_v<<<dim3(TT / 64, NH), 256, 0, stream>>>(rA, Vtg);
  // 4. attention (K/Q direct from kqz) -> hv bf16
  attn4<<<512, 256, 0, stream>>>(rA, Vtg, hv_b);
  // 5. proj split-4 -> partials rA (kqz dead); grid 512 = 8*(4x16); 1.25MB/XCD
  gemm6<<<512, 256, 0, stream>>>(hv_b, wo_b, rA, rA,
      TT, DD, DD, DD / 4, 4, 16, 4);
  //    x2 = x + b_o + sum(p0..3);  h2 = LN2(x2)   (fused)
  reduce4_ln<<<TT, 256, 0, stream>>>(rA, b_o, x, ln2_w, ln2_b, x2, h_b);
  // 7. up split-2 -> partials rA/rB; grid 1024 = 8*(16x8); 3MB/XCD
  gemm6<<<1024, 256, 0, stream>>>(h_b, wup_b, rA, rB,
      TT, DFF, DD, DD / 2, 16, 8, 1);
  //    z1 = gelu(rA+rB+b_up) (bf16, in-place over rA)
  reduce2b<1><<<TT * DFF / 4 / 256, 256, 0, stream>>>(
      rA, rB, b_up, rA, DFF / 4);
  // 8. down split-8 -> partials rB (4x) + pB2 (4x); grid 1024 = 8*(8x16); 3MB/XCD
  gemm6<<<1024, 256, 0, stream>>>(rA, wdn_b, rB, pB2,
      TT, DD, DFF, DFF / 8, 8, 16, 4);
  //    out = x2 + b_dn + sum(all 8 partials)
  reduce8<<<TT * DD / 4 / 256, 256, 0, stream>>>(rB, pB2, b_dn, x2, out);
}